// Round 8
// baseline (233.979 us; speedup 1.0000x reference)
//
#include <hip/hip_runtime.h>

// HexConv2d implicit GEMM, v14: port to mfma_f32_32x32x16_bf16.
// 7-round evidence: MfmaUtil pinned 38-40% across occupancy 17-40%, VMEM-free
// inner loop, staging depth 1-2 -> duration = 2.2x the per-SIMD 16x16 pipe
// floor (87k cyc) regardless of structure. 32x32x16 attacks the floor AND the
// ratio: per-SIMD rate 1017 vs 844 FLOP/cyc (m119 2495 TF) -> floor 72k cyc
// (30us); instruction count halves; MFMA pipe-work per ds_read_b128 DOUBLES
// (10 MFMA x 32 cyc per 5-read step vs 20 x 19.4 per 10-read tap).
// K-layout safety: A and B share the assumed k=(lane>>5)*8+j mapping -> any
// shared K permutation cancels in the contraction; only C/D layout matters
// (HW-verified m74/m101: col=lane&31, row=(reg&3)+8*(reg>>2)+4*(lane>>5)).
// LDS layout/staging/swizzle byte-identical to v13 (0-conflict verified);
// 32-row B-read keeps the same (parity,part) uniformity under swz=(r>>1)&3.
// Geometry: PT=160, 17-seg kc slots, 3-slot ring staged 2 ahead, 4 waves x
// (64och = 2x32-tile x 160px = 5x32-frag), acc[2][5] f32x16 = 160 regs ->
// 2 waves/SIMD from 2 desynced blocks; grid 16x32 = 2/CU exact. af register
// ring (1 step ahead) kept from v13. Weights repacked for 32-och A-frags.

typedef __attribute__((ext_vector_type(8)))  short short8;
typedef __attribute__((ext_vector_type(4)))  short short4v;
typedef __attribute__((ext_vector_type(4)))  float floatx4;
typedef __attribute__((ext_vector_type(16))) float floatx16;

#define NPIX   2401
#define W50    50
#define PREAL  2450      // 49 rows * 50
#define XBLEAD 56
#define XBROWS 2672      // padded rows per batch: [-56, 2616)
#define PT14   160       // pixels per block
#define NSEG14 17        // 272 window rows: [P0-56, P0+216); max tap row 209
#define SLOT14 (NSEG14*1024)      // 17408 B per kc slot
#define XB3_BYTES ((size_t)32*XBROWS*256*2)   // 43,778,048
#define WP_BYTES  917504ULL
#define WS_NEED3  (XB3_BYTES + WP_BYTES)
#define NPADROW 271      // 56 apron + 49 col-49 + 166 tail rows per batch

// merged-prep block ranges
#define X4_BLKS 4864     // 38*4*32
#define Z_BLKS  1084     // 32*271*32 / 256 = 1084 exactly
#define W_BLKS  224
#define PREP_BLKS (X4_BLKS + Z_BLKS + W_BLKS)   // 6172

__device__ __forceinline__ unsigned short f2bf(float f) {
  unsigned u = __builtin_bit_cast(unsigned, f);
  u += 0x7fffu + ((u >> 16) & 1u);          // RNE
  return (unsigned short)(u >> 16);
}

// OLD packing (16-och tiles) -- used only by the v1 fallback path.
__device__ __forceinline__ void prep_w_body(const float* __restrict__ w,
                                            unsigned short* __restrict__ wp, int tt) {
  int l  = tt & 63;
  int ot = (tt >> 6) & 15;
  int kc = (tt >> 10) & 7;
  int n  = tt >> 13;
  int o  = ot * 16 + (l & 15);
  int cb = kc * 32 + ((l >> 4) * 8);
  const float* src = w + (size_t)(o * 256 + cb) * 7 + n;
  short8 pk;
#pragma unroll
  for (int j = 0; j < 8; ++j) pk[j] = (short)f2bf(src[j * 7]);
  ((short8*)wp)[tt] = pk;
}

// NEW packing for 32x32x16 A-frags: frag f2 = (n*16 + g)*8 + ot2, g = 16-ch
// group (0..15), ot2 = 32-och tile (0..7). Lane l holds 8 bf16:
// W[ot2*32+(l&31)][g*16+(l>>5)*8+j][n].
__device__ __forceinline__ void prep_w2_body(const float* __restrict__ w,
                                             unsigned short* __restrict__ wp, int tt) {
  int l   = tt & 63;
  int ot2 = (tt >> 6) & 7;
  int g   = (tt >> 9) & 15;
  int n   = tt >> 13;
  int o   = ot2 * 32 + (l & 31);
  int c0  = g * 16 + ((l >> 5) * 8);
  const float* src = w + (size_t)(o * 256 + c0) * 7 + n;
  short8 pk;
#pragma unroll
  for (int j = 0; j < 8; ++j) pk[j] = (short)f2bf(src[j * 7]);
  ((short8*)wp)[tt] = pk;
}

// ---------------- merged prep: x-transpose | pad-zero | w-pack ----------------
__global__ __launch_bounds__(256)
void prep_all(const float* __restrict__ x, const float* __restrict__ w,
              unsigned short* __restrict__ xb, unsigned short* __restrict__ wp) {
  __shared__ unsigned short t[64][68];      // used by x4 path only
  const int tid = threadIdx.x;
  const int blk = blockIdx.x;

  if (blk < X4_BLKS) {
    // ---- prep_x4 body: x [b][c][2401] fp32 -> xb [b][row][256c] bf16 (masked)
    const int l = blk;
    const int span = l % 38, cg = (l / 38) & 3, b = l / 152;
    const int s0 = span * 64;
    {
      const int chl = tid >> 2, i4 = tid & 3;
      const float* src = x + ((size_t)(b * 256 + cg * 64 + chl)) * NPIX;
      const int rbase = s0 + i4 * 16;
#pragma unroll
      for (int it = 0; it < 4; ++it) {
        int r = rbase + it * 4;
        float vv[4] = {0.f, 0.f, 0.f, 0.f};
        if (r + 3 < NPIX) {
          float4 v = *(const float4*)(src + r);
          vv[0] = v.x; vv[1] = v.y; vv[2] = v.z; vv[3] = v.w;
        } else {
#pragma unroll
          for (int e = 0; e < 4; ++e) if (r + e < NPIX) vv[e] = src[r + e];
        }
        short4v u = {0, 0, 0, 0};
#pragma unroll
        for (int e = 0; e < 4; ++e) {
          int re = r + e;
          unsigned short uu = 0;
          if (re < NPIX) {
            int h = re / 49, ww = re - h * 49, s = h + ww;
            if (s >= 24 && s <= 72) uu = f2bf(vv[e]);
          }
          u[e] = (short)uu;
        }
        *(short4v*)&t[chl][i4 * 16 + it * 4] = u;
      }
    }
    __syncthreads();
    const int pp = tid >> 3;   // pixel pair 0..31
    const int co = tid & 7;    // channel octet 0..7
    unsigned d[8];
#pragma unroll
    for (int k = 0; k < 8; ++k) d[k] = *(const unsigned*)&t[co * 8 + k][pp * 2];
    uint4 lo, hi;
    {
      unsigned l0[4], h0[4];
#pragma unroll
      for (int m = 0; m < 4; ++m) {
        unsigned a = d[2 * m], bq = d[2 * m + 1];
        l0[m] = (a & 0xffffu) | (bq << 16);
        h0[m] = (a >> 16) | (bq & 0xffff0000u);
      }
      lo = make_uint4(l0[0], l0[1], l0[2], l0[3]);
      hi = make_uint4(h0[0], h0[1], h0[2], h0[3]);
    }
    const int r_lo = s0 + pp * 2, r_hi = r_lo + 1;
    if (r_lo < NPIX) {
      int prow = r_lo + r_lo / 49 + XBLEAD;
      *(uint4*)(xb + ((size_t)b * XBROWS + prow) * 256 + cg * 64 + co * 8) = lo;
    }
    if (r_hi < NPIX) {
      int prow = r_hi + r_hi / 49 + XBLEAD;
      *(uint4*)(xb + ((size_t)b * XBROWS + prow) * 256 + cg * 64 + co * 8) = hi;
    }
  } else if (blk < X4_BLKS + Z_BLKS) {
    // ---- zero_pads5 body: zero only the pad rows of xb
    int idx = (blk - X4_BLKS) * 256 + tid;
    if (idx >= 32 * NPADROW * 32) return;
    int c16 = idx & 31;
    int rr  = idx >> 5;
    int pr  = rr % NPADROW;
    int b   = rr / NPADROW;
    int row;
    if (pr < 56)        row = pr;
    else if (pr < 105)  row = 105 + 50 * (pr - 56);
    else                row = 2506 + (pr - 105);
    short8 z = {0,0,0,0,0,0,0,0};
    *(short8*)(xb + ((size_t)b * XBROWS + row) * 256 + c16 * 8) = z;
  } else {
    // ---- NEW w packing for v14
    prep_w2_body(w, wp, (blk - X4_BLKS - Z_BLKS) * 256 + tid);
  }
}

// standalone OLD w-pack for the fallback path (no xb workspace)
__global__ void prep_w_kernel(const float* __restrict__ w, unsigned short* __restrict__ wp) {
  prep_w_body(w, wp, blockIdx.x * 256 + threadIdx.x);
}

// ---------------- main v14 (32x32x16) ----------------
__global__ __launch_bounds__(256, 2)
void hexconv_v14(const unsigned short* __restrict__ xb,
                 const unsigned short* __restrict__ wp,
                 const float* __restrict__ bias,
                 float* __restrict__ out) {
  __shared__ __attribute__((aligned(16))) unsigned char smem[3 * SLOT14];  // 52224 B

  const int tid   = threadIdx.x;
  const int lane  = tid & 63;
  const int wv    = tid >> 6;     // 0..3: wave owns och [wv*64, wv*64+64)
  const int col32 = lane & 31;    // px within 32-px frag
  const int hi    = lane >> 5;    // K-half selector (ch octet within 16-ch grp)

  const int pt = blockIdx.x;          // 0..15
  const int b  = blockIdx.y;
  const int P0 = pt * PT14;
  const int phase = (pt + b) & 7;     // kc start offset: desync blocks

  // tap offsets in pitch-50 padded space
  const int OFF[7] = {0, 50, 1, -49, -50, -1, 49};

  // B-frag LDS base addrs. Physical part bits (swz = stored part = logical ^
  // ((r>>1)&3), inherited from staging):
  //   bit4 = hi ^ ((rn>>1)&1),  bit5 = kk2 ^ ((rn>>2)&1)  (kk2 applied as XOR)
  // j (32-px step) adds j*2048; swizzle is j-invariant (32*64 = 2048, bits>=11).
  int ba[7];
#pragma unroll
  for (int n = 0; n < 7; ++n) {
    int rn = col32 + 56 + OFF[n];            // 6..137 (< 272-row window)
    ba[n] = rn * 64 + ((hi ^ ((rn >> 1) & 1)) << 4) + (((rn >> 2) & 1) << 5);
  }

  // staging: within a seg, lane l covers row 16s+(l>>2), LDS part l&3 (HW-forced),
  // global part swizzled so compute-side access lands conflict-free (v6-proven)
  const int gpart = (lane & 3) ^ ((lane >> 3) & 3);
  const char* gsrc0 = (const char*)(xb + ((size_t)b * XBROWS + (size_t)P0) * 256)
                      + (lane >> 2) * 512 + gpart * 16;

  // stage ONE kc into slot: 17 seg-units over 4 waves
  auto stage1 = [&](int slot, int kc) {
    char* ldsb = (char*)smem + slot * SLOT14;
    for (int u = wv; u < NSEG14; u += 4) {
      __builtin_amdgcn_global_load_lds(
          (const __attribute__((address_space(1))) unsigned int*)
              (gsrc0 + (size_t)u * 8192 + kc * 64),
          (__attribute__((address_space(3))) unsigned int*)(ldsb + u * 1024), 16, 0, 0);
    }
  };

  // A-frag base: this wave's 2 och-32 tiles are ot2 = wv*2, wv*2+1
  const char* wbA = (const char*)wp + (size_t)(wv * 2) * 1024 + lane * 16;

  short8 afr[2][2];          // af ring: 2 step-slots x 2 och-tiles (16 VGPR)
  floatx16 acc[2][5];
#pragma unroll
  for (int t = 0; t < 2; ++t)
#pragma unroll
    for (int j = 0; j < 5; ++j)
#pragma unroll
      for (int e = 0; e < 16; ++e) acc[t][j][e] = 0.f;

  // prologue: stage kc0->slot0, kc1->slot1; preload step-0 A-frags (n=0, g=2*kc0)
  stage1(0, phase);
  stage1(1, (1 + phase) & 7);
#pragma unroll
  for (int t = 0; t < 2; ++t)
    afr[0][t] = *(const short8*)(wbA + (size_t)((phase * 2) * 8 + t) * 1024);
  __syncthreads();

#pragma unroll 1
  for (int i = 0; i < 8; ++i) {
    const int ci  = (i + phase) & 7;
    const int cin = (i + 1 + phase) & 7;
    if (i < 6) stage1((i + 2) % 3, (i + 2 + phase) & 7);
    const char* slotp = (const char*)smem + (i % 3) * SLOT14;
#pragma unroll
    for (int s = 0; s < 14; ++s) {          // step = tap n (s>>1) x K-half kk2 (s&1)
      const int n   = s >> 1;
      const int kk2 = s & 1;
      const int cs  = s & 1;                 // af ring slot (14 even: next iter s=0 -> slot 0)
      const int ns  = cs ^ 1;
      // prefetch next step's A-frags into the other ring slot
      if (s < 13) {
        const int n2 = (s + 1) >> 1;
        const int g2 = ci * 2 + ((s + 1) & 1);
#pragma unroll
        for (int t = 0; t < 2; ++t)
          afr[ns][t] = *(const short8*)(wbA + (size_t)((n2 * 16 + g2) * 8 + t) * 1024);
      } else if (i < 7) {
        const int g2 = cin * 2;              // next iter, n=0, kk2=0
#pragma unroll
        for (int t = 0; t < 2; ++t)
          afr[ns][t] = *(const short8*)(wbA + (size_t)(g2 * 8 + t) * 1024);
      }
      const char* bp = slotp + (ba[n] ^ (kk2 << 5));
      short8 bfv[5];
#pragma unroll
      for (int j = 0; j < 5; ++j) bfv[j] = *(const short8*)(bp + j * 2048);
      __builtin_amdgcn_s_setprio(1);
#pragma unroll
      for (int j = 0; j < 5; ++j)
#pragma unroll
        for (int t = 0; t < 2; ++t)
          acc[t][j] = __builtin_amdgcn_mfma_f32_32x32x16_bf16(afr[cs][t], bfv[j], acc[t][j], 0, 0, 0);
      __builtin_amdgcn_s_setprio(0);
    }
    __syncthreads();
  }

  // epilogue. C/D layout (m74/m101): col=lane&31 = px-in-frag,
  // row = (reg&3) + 8*(reg>>2) + 4*hi -> och = wv*64 + t*32 + g4*8 + hi*4 + e.
  // Pre-add bias, then masked store; px = P0 + j*32 + col32.
#pragma unroll
  for (int t = 0; t < 2; ++t) {
#pragma unroll
    for (int g4 = 0; g4 < 4; ++g4) {
      floatx4 bv = *(const floatx4*)(bias + wv * 64 + t * 32 + g4 * 8 + hi * 4);
#pragma unroll
      for (int j = 0; j < 5; ++j)
#pragma unroll
        for (int e = 0; e < 4; ++e) acc[t][j][g4 * 4 + e] += bv[e];
    }
  }

#pragma unroll
  for (int j = 0; j < 5; ++j) {
    int p = P0 + j * 32 + col32;
    int h = p / W50;
    int w = p - h * W50;
    if (w >= 49 || p >= PREAL) continue;
    bool m = (h + w >= 24) && (h + w <= 72);
    int ridx = h * 49 + w;
#pragma unroll
    for (int t = 0; t < 2; ++t) {
#pragma unroll
      for (int g4 = 0; g4 < 4; ++g4) {
        int och0 = wv * 64 + t * 32 + g4 * 8 + hi * 4;
        float* dst = out + ((b * 256 + och0) * NPIX + ridx);
#pragma unroll
        for (int e = 0; e < 4; ++e) {
          float v = m ? acc[t][j][g4 * 4 + e] : 0.f;
          dst[e * NPIX] = v;
        }
      }
    }
  }
}

// ---------------- fallback v1 (ws too small; uses OLD wp layout) ----------------
#define PITCH  40
#define V1WIN  168
#define V1ZROW 168
__global__ __launch_bounds__(256)
void hexconv_v1(const float* __restrict__ x,
                const unsigned short* __restrict__ wp,
                const float* __restrict__ bias,
                float* __restrict__ out) {
  __shared__ unsigned short sm[(V1ZROW + 2) * PITCH];
  const int tid = threadIdx.x, lane = tid & 63, wv = tid >> 6;
  const int col = lane & 15, quad = lane >> 4;
  const int pt = blockIdx.x, b = blockIdx.y;
  const int P0 = pt * 64, win_start = P0 - 52;
  if (tid < PITCH * 2) sm[V1ZROW * PITCH + tid] = 0;
  const int OFF[7] = {0, 49, 1, -48, -49, -1, 48};
  const int DXP = (1 << 2) | (1 << 3), DXN = (1 << 5) | (1 << 6);
  int baddr[4][7];
#pragma unroll
  for (int j = 0; j < 4; ++j) {
    int pix = P0 + j * 16 + col;
    int wj = pix % 49;
    int rowbase = pix - win_start;
#pragma unroll
    for (int n = 0; n < 7; ++n) {
      bool bad = (((DXP >> n) & 1) && wj == 48) || (((DXN >> n) & 1) && wj == 0);
      int row = bad ? V1ZROW : (rowbase + OFF[n]);
      baddr[j][n] = row * (PITCH * 2) + quad * 16;
    }
  }
  int sp[3], sgp[3]; bool sok[3];
#pragma unroll
  for (int pi = 0; pi < 3; ++pi) {
    int p = lane + pi * 64, gp = win_start + p;
    sp[pi] = p; sgp[pi] = gp;
    bool hm = false;
    if (gp >= 0 && gp < NPIX) { int h = gp / 49, w = gp - h * 49, s = h + w; hm = (s >= 24 && s <= 72); }
    sok[pi] = (p < V1WIN) && hm;
  }
  floatx4 acc[4][4];
#pragma unroll
  for (int i = 0; i < 4; ++i)
#pragma unroll
    for (int j = 0; j < 4; ++j) acc[i][j] = (floatx4){0.f, 0.f, 0.f, 0.f};
  const short8* wpv = (const short8*)wp;
  const int wslot = wv * 4;
  for (int kc = 0; kc < 8; ++kc) {
    __syncthreads();
#pragma unroll
    for (int ci = 0; ci < 8; ++ci) {
      int c = ci * 4 + wv;
      const float* src = x + ((size_t)(b * 256 + kc * 32 + c)) * NPIX;
#pragma unroll
      for (int pi = 0; pi < 3; ++pi) {
        if (sp[pi] < V1WIN) {
          float v = sok[pi] ? src[sgp[pi]] : 0.f;
          sm[sp[pi] * PITCH + c] = f2bf(v);
        }
      }
    }
    __syncthreads();
#pragma unroll
    for (int n = 0; n < 7; ++n) {
      short8 af[4];
#pragma unroll
      for (int i = 0; i < 4; ++i)
        af[i] = wpv[((size_t)((n * 8 + kc) * 16 + wslot + i)) * 64 + lane];
      short8 bf[4];
#pragma unroll
      for (int j = 0; j < 4; ++j)
        bf[j] = *(const short8*)((const char*)sm + baddr[j][n]);
#pragma unroll
      for (int i = 0; i < 4; ++i)
#pragma unroll
        for (int j = 0; j < 4; ++j)
          acc[i][j] = __builtin_amdgcn_mfma_f32_16x16x32_bf16(af[i], bf[j], acc[i][j], 0, 0, 0);
    }
  }
  const int ob = wv * 64;
  floatx4 bv[4];
#pragma unroll
  for (int i = 0; i < 4; ++i)
    bv[i] = *(const floatx4*)(bias + ob + i * 16 + quad * 4);
#pragma unroll
  for (int j = 0; j < 4; ++j) {
    int pix = P0 + j * 16 + col;
    if (pix >= NPIX) continue;
    int h = pix / 49, w = pix - h * 49;
    bool m = (h + w >= 24 && h + w <= 72);
#pragma unroll
    for (int i = 0; i < 4; ++i) {
      int o = ob + i * 16 + quad * 4;
      float* dst = out + ((size_t)(b * 256 + o)) * NPIX + pix;
#pragma unroll
      for (int r = 0; r < 4; ++r) {
        float v = m ? (acc[i][j][r] + bv[i][r]) : 0.f;
        dst[(size_t)r * NPIX] = v;
      }
    }
  }
}

extern "C" void kernel_launch(void* const* d_in, const int* in_sizes, int n_in,
                              void* d_out, int out_size, void* d_ws, size_t ws_size,
                              hipStream_t stream) {
  const float* x    = (const float*)d_in[0];   // [32,256,49,49]
  const float* w    = (const float*)d_in[1];   // [256,256,7]
  const float* bias = (const float*)d_in[2];   // [256]
  float* out = (float*)d_out;

  if (ws_size >= WS_NEED3) {
    unsigned short* xb = (unsigned short*)d_ws;
    unsigned short* wp = (unsigned short*)((char*)d_ws + XB3_BYTES);
    prep_all<<<PREP_BLKS, 256, 0, stream>>>(x, w, xb, wp);
    hexconv_v14<<<dim3(16, 32), 256, 0, stream>>>(xb, wp, bias, out);
  } else {
    unsigned short* wp = (unsigned short*)d_ws;
    prep_w_kernel<<<224, 256, 0, stream>>>(w, wp);
    hexconv_v1<<<dim3(38, 32), 256, 0, stream>>>(x, wp, bias, out);
  }
}

// Round 9
// 230.688 us; speedup vs baseline: 1.0143x; 1.0143x over previous
//
#include <hip/hip_runtime.h>

// HexConv2d implicit GEMM, bf16 MFMA 16x16x32.
// v15 = v13 (77.5us, best) + ONE change: xb staging loads marked NON-TEMPORAL
// (global_load_lds aux=2 -> nt). Theory: weights (896KB, written by prep
// blocks spread over all 8 XCDs) are evicted from each XCD's 4MB L2 by the
// 44MB xb stream; af loads then cost L3/HBM latency (300-900cy) > the ~400cy
// prefetch slack -> per-tap stall on the critical path. This is the only
// theory consistent with 9 rounds of structure-invariant MfmaUtil 38-40%
// (occupancy 17-40%, reg headroom, barrier cadence, MFMA shape all falsified).
// NT on xb (read ~1.3x then dead) preserves L2 for the weight set.
// v14 side-finding: 32x32 MFMA's B-frag (32-row, single-slot per quarter-wave)
// costs 4 cyc/ds_read in bank conflicts -> 16x16 retained.

typedef __attribute__((ext_vector_type(8))) short short8;
typedef __attribute__((ext_vector_type(4))) short short4v;
typedef __attribute__((ext_vector_type(4))) float floatx4;

#define NPIX   2401
#define W50    50
#define PREAL  2450      // 49 rows * 50
#define XBLEAD 56
#define XBROWS 2672      // padded rows per batch: [-56, 2616)
#define PT13   80        // pixels per block
#define NSEG13 12        // 192 window rows: [P0-56, P0+136); max tap row 185
#define BUF13  (NSEG13*1024)      // 12288 B per kc slot
#define XB3_BYTES ((size_t)32*XBROWS*256*2)   // 43,778,048
#define WP_BYTES  917504ULL
#define WS_NEED3  (XB3_BYTES + WP_BYTES)
#define NPADROW 271      // 56 apron + 49 col-49 + 166 tail rows per batch

// merged-prep block ranges
#define X4_BLKS 4864     // 38*4*32
#define Z_BLKS  1084     // 32*271*32 / 256 = 1084 exactly
#define W_BLKS  224
#define PREP_BLKS (X4_BLKS + Z_BLKS + W_BLKS)   // 6172

__device__ __forceinline__ unsigned short f2bf(float f) {
  unsigned u = __builtin_bit_cast(unsigned, f);
  u += 0x7fffu + ((u >> 16) & 1u);          // RNE
  return (unsigned short)(u >> 16);
}

__device__ __forceinline__ void prep_w_body(const float* __restrict__ w,
                                            unsigned short* __restrict__ wp, int tt) {
  int l  = tt & 63;
  int ot = (tt >> 6) & 15;
  int kc = (tt >> 10) & 7;
  int n  = tt >> 13;
  int o  = ot * 16 + (l & 15);
  int cb = kc * 32 + ((l >> 4) * 8);
  const float* src = w + (size_t)(o * 256 + cb) * 7 + n;
  short8 pk;
#pragma unroll
  for (int j = 0; j < 8; ++j) pk[j] = (short)f2bf(src[j * 7]);
  ((short8*)wp)[tt] = pk;
}

// ---------------- merged prep: x-transpose | pad-zero | w-pack ----------------
__global__ __launch_bounds__(256)
void prep_all(const float* __restrict__ x, const float* __restrict__ w,
              unsigned short* __restrict__ xb, unsigned short* __restrict__ wp) {
  __shared__ unsigned short t[64][68];      // used by x4 path only
  const int tid = threadIdx.x;
  const int blk = blockIdx.x;

  if (blk < X4_BLKS) {
    // ---- prep_x4 body: x [b][c][2401] fp32 -> xb [b][row][256c] bf16 (masked)
    const int l = blk;
    const int span = l % 38, cg = (l / 38) & 3, b = l / 152;
    const int s0 = span * 64;
    {
      const int chl = tid >> 2, i4 = tid & 3;
      const float* src = x + ((size_t)(b * 256 + cg * 64 + chl)) * NPIX;
      const int rbase = s0 + i4 * 16;
#pragma unroll
      for (int it = 0; it < 4; ++it) {
        int r = rbase + it * 4;
        float vv[4] = {0.f, 0.f, 0.f, 0.f};
        if (r + 3 < NPIX) {
          float4 v = *(const float4*)(src + r);
          vv[0] = v.x; vv[1] = v.y; vv[2] = v.z; vv[3] = v.w;
        } else {
#pragma unroll
          for (int e = 0; e < 4; ++e) if (r + e < NPIX) vv[e] = src[r + e];
        }
        short4v u = {0, 0, 0, 0};
#pragma unroll
        for (int e = 0; e < 4; ++e) {
          int re = r + e;
          unsigned short uu = 0;
          if (re < NPIX) {
            int h = re / 49, ww = re - h * 49, s = h + ww;
            if (s >= 24 && s <= 72) uu = f2bf(vv[e]);
          }
          u[e] = (short)uu;
        }
        *(short4v*)&t[chl][i4 * 16 + it * 4] = u;
      }
    }
    __syncthreads();
    const int pp = tid >> 3;   // pixel pair 0..31
    const int co = tid & 7;    // channel octet 0..7
    unsigned d[8];
#pragma unroll
    for (int k = 0; k < 8; ++k) d[k] = *(const unsigned*)&t[co * 8 + k][pp * 2];
    uint4 lo, hi;
    {
      unsigned l0[4], h0[4];
#pragma unroll
      for (int m = 0; m < 4; ++m) {
        unsigned a = d[2 * m], bq = d[2 * m + 1];
        l0[m] = (a & 0xffffu) | (bq << 16);
        h0[m] = (a >> 16) | (bq & 0xffff0000u);
      }
      lo = make_uint4(l0[0], l0[1], l0[2], l0[3]);
      hi = make_uint4(h0[0], h0[1], h0[2], h0[3]);
    }
    const int r_lo = s0 + pp * 2, r_hi = r_lo + 1;
    if (r_lo < NPIX) {
      int prow = r_lo + r_lo / 49 + XBLEAD;
      *(uint4*)(xb + ((size_t)b * XBROWS + prow) * 256 + cg * 64 + co * 8) = lo;
    }
    if (r_hi < NPIX) {
      int prow = r_hi + r_hi / 49 + XBLEAD;
      *(uint4*)(xb + ((size_t)b * XBROWS + prow) * 256 + cg * 64 + co * 8) = hi;
    }
  } else if (blk < X4_BLKS + Z_BLKS) {
    // ---- zero_pads5 body: zero only the pad rows of xb
    int idx = (blk - X4_BLKS) * 256 + tid;
    if (idx >= 32 * NPADROW * 32) return;
    int c16 = idx & 31;
    int rr  = idx >> 5;
    int pr  = rr % NPADROW;
    int b   = rr / NPADROW;
    int row;
    if (pr < 56)        row = pr;
    else if (pr < 105)  row = 105 + 50 * (pr - 56);
    else                row = 2506 + (pr - 105);
    short8 z = {0,0,0,0,0,0,0,0};
    *(short8*)(xb + ((size_t)b * XBROWS + row) * 256 + c16 * 8) = z;
  } else {
    // ---- prep_w body
    prep_w_body(w, wp, (blk - X4_BLKS - Z_BLKS) * 256 + tid);
  }
}

// standalone w-pack for the fallback path (no xb workspace)
__global__ void prep_w_kernel(const float* __restrict__ w, unsigned short* __restrict__ wp) {
  prep_w_body(w, wp, blockIdx.x * 256 + threadIdx.x);
}

// one kc-iteration: consume af ring parity JPAR, prefetch next tap's frags.
// DO_STAGE: issue stage for iter i+2. DO_PRE_LAST: at tap 6, prefetch tap0 of
// the NEXT kc (skipped only on the final iteration).
#define HEX_ITER(IVAL, JPAR, DO_STAGE, DO_PRE_LAST)                           \
  {                                                                           \
    const int i_ = (IVAL);                                                    \
    if (DO_STAGE) stage1((i_ + 2) % 3, (i_ + 2 + phase) & 7);                 \
    const int kcc_ = (i_ + phase) & 7;                                        \
    const int kcn_ = (i_ + 1 + phase) & 7;                                    \
    const char* bufp_ = (const char*)smem + (i_ % 3) * BUF13;                 \
    _Pragma("unroll")                                                         \
    for (int n = 0; n < 7; ++n) {                                             \
      const int cs = (n + (JPAR)) & 1;                                        \
      const int ns = cs ^ 1;                                                  \
      if (n < 6) {                                                            \
        _Pragma("unroll")                                                     \
        for (int ii = 0; ii < 4; ++ii)                                        \
          afr[ns][ii] = *(const short8*)(wbase +                              \
              (size_t)(((n + 1) * 8 + kcc_) * 16 + ii) * 1024);               \
      } else if (DO_PRE_LAST) {                                               \
        _Pragma("unroll")                                                     \
        for (int ii = 0; ii < 4; ++ii)                                        \
          afr[ns][ii] = *(const short8*)(wbase +                              \
              (size_t)((kcn_ * 16) + ii) * 1024);                             \
      }                                                                       \
      const char* bp_ = bufp_ + ba[n];                                        \
      short8 bfv[5];                                                          \
      _Pragma("unroll")                                                       \
      for (int j = 0; j < 5; ++j) bfv[j] = *(const short8*)(bp_ + j * 1024);  \
      __builtin_amdgcn_s_setprio(1);                                          \
      _Pragma("unroll")                                                       \
      for (int j = 0; j < 5; ++j)                                             \
        _Pragma("unroll")                                                     \
        for (int ii = 0; ii < 4; ++ii)                                        \
          acc[ii][j] = __builtin_amdgcn_mfma_f32_16x16x32_bf16(               \
              afr[cs][ii], bfv[j], acc[ii][j], 0, 0, 0);                      \
      __builtin_amdgcn_s_setprio(0);                                          \
    }                                                                         \
  }

// ---------------- main v15 ----------------
__global__ __launch_bounds__(256, 2)
void hexconv_v15(const unsigned short* __restrict__ xb,
                 const unsigned short* __restrict__ wp,
                 const float* __restrict__ bias,
                 float* __restrict__ out) {
  __shared__ __attribute__((aligned(16))) unsigned char smem[3 * BUF13];  // 36864 B

  const int tid  = threadIdx.x;
  const int lane = tid & 63;
  const int wv   = tid >> 6;    // 0..3: wave owns och [wv*64, wv*64+64)
  const int col  = lane & 15;
  const int quad = lane >> 4;

  // pt relabel: XCD x (= bx%8 under round-robin dispatch) owns pt in [4x,4x+4)
  const int bx = blockIdx.x;          // 0..31
  const int pt = (bx & 7) * 4 + (bx >> 3);
  const int b  = blockIdx.y;
  const int P0 = pt * PT13;
  const int phase = (pt + b) & 7;     // kc start offset: desync blocks

  // tap offsets in pitch-50 padded space
  const int OFF[7] = {0, 50, 1, -49, -50, -1, 49};

  // B-frag LDS base addresses within a kc slot (j adds j*1024 = 16 rows)
  int ba[7];
#pragma unroll
  for (int n = 0; n < 7; ++n) {
    int r0 = col + 56 + OFF[n];              // 6..121 (< 192-row window)
    int r64 = r0 << 6;
    ba[n] = (r64 + quad * 16) ^ ((r64 >> 3) & 0x30);
  }

  // staging: within a seg, lane l covers row 16s+(l>>2), LDS part l&3 (HW-forced),
  // global part swizzled so compute-side XOR lands conflict-free
  const int gpart = (lane & 3) ^ ((lane >> 3) & 3);
  const char* gsrc0 = (const char*)(xb + ((size_t)b * XBROWS + (size_t)P0) * 256)
                      + (lane >> 2) * 512 + gpart * 16;

  // stage ONE kc into slot: 12 seg-units over 4 waves (3 each).
  // aux=2 -> NT: xb lines are read-once; keep them out of L2 so the 896KB
  // weight set stays L2-resident for the per-tap af loads.
  auto stage1 = [&](int slot, int kc) {
    char* ldsb = (char*)smem + slot * BUF13;
    for (int u = wv; u < NSEG13; u += 4) {
      __builtin_amdgcn_global_load_lds(
          (const __attribute__((address_space(1))) unsigned int*)
              (gsrc0 + (size_t)u * 8192 + kc * 64),
          (__attribute__((address_space(3))) unsigned int*)(ldsb + u * 1024), 16, 0, 2);
    }
  };

  // A-frag base: this wave's 4 och tiles start at ot = wv*4
  const char* wbase = (const char*)wp + (size_t)(wv * 4) * 1024 + lane * 16;

  short8 afr[2][4];          // af ring: 2 tap-sets x 4 och-tiles (32 VGPR)
  floatx4 acc[4][5];
#pragma unroll
  for (int ii = 0; ii < 4; ++ii)
#pragma unroll
    for (int j = 0; j < 5; ++j) acc[ii][j] = (floatx4){0.f, 0.f, 0.f, 0.f};

  // prologue: stage kc0->slot0, kc1->slot1; preload tap0 frags of kc0
  stage1(0, phase);
  stage1(1, (1 + phase) & 7);
#pragma unroll
  for (int ii = 0; ii < 4; ++ii)
    afr[0][ii] = *(const short8*)(wbase + (size_t)((phase * 16) + ii) * 1024);
  __syncthreads();

#pragma unroll 1
  for (int p = 0; p < 3; ++p) {
    HEX_ITER(2 * p,     0, true, true);
    __syncthreads();
    HEX_ITER(2 * p + 1, 1, true, true);
    __syncthreads();
  }
  HEX_ITER(6, 0, false, true);
  __syncthreads();
  HEX_ITER(7, 1, false, false);

  // epilogue: bias pre-add, masked store. o = wv*64+ii*16+quad*4+rr,
  // padded pix = P0 + j*16 + col
  const int ob = wv * 64;
#pragma unroll
  for (int ii = 0; ii < 4; ++ii) {
    floatx4 bv = *(const floatx4*)(bias + ob + ii * 16 + quad * 4);
#pragma unroll
    for (int j = 0; j < 5; ++j)
#pragma unroll
      for (int rr = 0; rr < 4; ++rr) acc[ii][j][rr] += bv[rr];
  }

#pragma unroll
  for (int j = 0; j < 5; ++j) {
    int p = P0 + j * 16 + col;
    int h = p / W50;
    int w = p - h * W50;
    if (w >= 49 || p >= PREAL) continue;
    bool m = (h + w >= 24) && (h + w <= 72);
    int ridx = h * 49 + w;
#pragma unroll
    for (int ii = 0; ii < 4; ++ii) {
      float* dst = out + ((b * 256 + ob + ii * 16 + quad * 4) * NPIX + ridx);
#pragma unroll
      for (int rr = 0; rr < 4; ++rr) {
        float v = m ? acc[ii][j][rr] : 0.f;
        dst[rr * NPIX] = v;
      }
    }
  }
}

// ---------------- fallback v1 (ws too small) ----------------
#define PITCH  40
#define V1WIN  168
#define V1ZROW 168
__global__ __launch_bounds__(256)
void hexconv_v1(const float* __restrict__ x,
                const unsigned short* __restrict__ wp,
                const float* __restrict__ bias,
                float* __restrict__ out) {
  __shared__ unsigned short sm[(V1ZROW + 2) * PITCH];
  const int tid = threadIdx.x, lane = tid & 63, wv = tid >> 6;
  const int col = lane & 15, quad = lane >> 4;
  const int pt = blockIdx.x, b = blockIdx.y;
  const int P0 = pt * 64, win_start = P0 - 52;
  if (tid < PITCH * 2) sm[V1ZROW * PITCH + tid] = 0;
  const int OFF[7] = {0, 49, 1, -48, -49, -1, 48};
  const int DXP = (1 << 2) | (1 << 3), DXN = (1 << 5) | (1 << 6);
  int baddr[4][7];
#pragma unroll
  for (int j = 0; j < 4; ++j) {
    int pix = P0 + j * 16 + col;
    int wj = pix % 49;
    int rowbase = pix - win_start;
#pragma unroll
    for (int n = 0; n < 7; ++n) {
      bool bad = (((DXP >> n) & 1) && wj == 48) || (((DXN >> n) & 1) && wj == 0);
      int row = bad ? V1ZROW : (rowbase + OFF[n]);
      baddr[j][n] = row * (PITCH * 2) + quad * 16;
    }
  }
  int sp[3], sgp[3]; bool sok[3];
#pragma unroll
  for (int pi = 0; pi < 3; ++pi) {
    int p = lane + pi * 64, gp = win_start + p;
    sp[pi] = p; sgp[pi] = gp;
    bool hm = false;
    if (gp >= 0 && gp < NPIX) { int h = gp / 49, w = gp - h * 49, s = h + w; hm = (s >= 24 && s <= 72); }
    sok[pi] = (p < V1WIN) && hm;
  }
  floatx4 acc[4][4];
#pragma unroll
  for (int i = 0; i < 4; ++i)
#pragma unroll
    for (int j = 0; j < 4; ++j) acc[i][j] = (floatx4){0.f, 0.f, 0.f, 0.f};
  const short8* wpv = (const short8*)wp;
  const int wslot = wv * 4;
  for (int kc = 0; kc < 8; ++kc) {
    __syncthreads();
#pragma unroll
    for (int ci = 0; ci < 8; ++ci) {
      int c = ci * 4 + wv;
      const float* src = x + ((size_t)(b * 256 + kc * 32 + c)) * NPIX;
#pragma unroll
      for (int pi = 0; pi < 3; ++pi) {
        if (sp[pi] < V1WIN) {
          float v = sok[pi] ? src[sgp[pi]] : 0.f;
          sm[sp[pi] * PITCH + c] = f2bf(v);
        }
      }
    }
    __syncthreads();
#pragma unroll
    for (int n = 0; n < 7; ++n) {
      short8 af[4];
#pragma unroll
      for (int i = 0; i < 4; ++i)
        af[i] = wpv[((size_t)((n * 8 + kc) * 16 + wslot + i)) * 64 + lane];
      short8 bf[4];
#pragma unroll
      for (int j = 0; j < 4; ++j)
        bf[j] = *(const short8*)((const char*)sm + baddr[j][n]);
#pragma unroll
      for (int i = 0; i < 4; ++i)
#pragma unroll
        for (int j = 0; j < 4; ++j)
          acc[i][j] = __builtin_amdgcn_mfma_f32_16x16x32_bf16(af[i], bf[j], acc[i][j], 0, 0, 0);
    }
  }
  const int ob = wv * 64;
  floatx4 bv[4];
#pragma unroll
  for (int i = 0; i < 4; ++i)
    bv[i] = *(const floatx4*)(bias + ob + i * 16 + quad * 4);
#pragma unroll
  for (int j = 0; j < 4; ++j) {
    int pix = P0 + j * 16 + col;
    if (pix >= NPIX) continue;
    int h = pix / 49, w = pix - h * 49;
    bool m = (h + w >= 24 && h + w <= 72);
#pragma unroll
    for (int i = 0; i < 4; ++i) {
      int o = ob + i * 16 + quad * 4;
      float* dst = out + ((size_t)(b * 256 + o)) * NPIX + pix;
#pragma unroll
      for (int r = 0; r < 4; ++r) {
        float v = m ? (acc[i][j][r] + bv[i][r]) : 0.f;
        dst[(size_t)r * NPIX] = v;
      }
    }
  }
}

extern "C" void kernel_launch(void* const* d_in, const int* in_sizes, int n_in,
                              void* d_out, int out_size, void* d_ws, size_t ws_size,
                              hipStream_t stream) {
  const float* x    = (const float*)d_in[0];   // [32,256,49,49]
  const float* w    = (const float*)d_in[1];   // [256,256,7]
  const float* bias = (const float*)d_in[2];   // [256]
  float* out = (float*)d_out;

  if (ws_size >= WS_NEED3) {
    unsigned short* xb = (unsigned short*)d_ws;
    unsigned short* wp = (unsigned short*)((char*)d_ws + XB3_BYTES);
    prep_all<<<PREP_BLKS, 256, 0, stream>>>(x, w, xb, wp);
    hexconv_v15<<<dim3(32, 32), 256, 0, stream>>>(xb, wp, bias, out);
  } else {
    unsigned short* wp = (unsigned short*)d_ws;
    prep_w_kernel<<<224, 256, 0, stream>>>(w, wp);
    hexconv_v1<<<dim3(38, 32), 256, 0, stream>>>(x, wp, bias, out);
  }
}